// Round 10
// baseline (341.961 us; speedup 1.0000x reference)
//
#include <hip/hip_runtime.h>

// CausalSelfAttention B=4, N=2048, D=1024, scale 1/32.
// f16 convert(+zero l/ready) -> fused QKV GEMM (128x128, BK=64) ->
// ONE fused S+PV dispatch (R10): S blocks (544, bm-ascending) compute
// P_unnorm = exp(mask(QK^T/32)) + atomic row sums, then threadfence +
// atomicAdd(ready[bz][bm]); PV blocks (512) spin on ready[bz][bm]==bm+1,
// then compute (P V)/l. Deadlock-free: 32KB LDS + 88 VGPR -> 5 blocks/CU
// capacity, grid 1056 <= 1280 so all blocks co-resident by arithmetic.
// R4-R9 showed S/PV invariant (~160us) under tile/dbuf/stream/XCD changes:
// the limit was ~2 resident blocks/CU per serial dispatch; fusion overlaps
// the two grids (~4.1 blocks/CU) and removes the inter-kernel barrier.

typedef __attribute__((ext_vector_type(8))) _Float16 half8;
typedef __attribute__((ext_vector_type(4))) _Float16 half4v;
typedef __attribute__((ext_vector_type(4))) float floatx4;

#define AS1 __attribute__((address_space(1)))
#define AS3 __attribute__((address_space(3)))

__device__ __forceinline__ void load16_lds(void* lds, const void* g) {
  __builtin_amdgcn_global_load_lds((AS1 void*)g, (AS3 void*)lds, 16, 0, 0);
}

// ---------------------------------------------------------------- conv + zero

__global__ __launch_bounds__(256)
void conv_f32_f16(const float* __restrict__ in, _Float16* __restrict__ out,
                  float* __restrict__ l) {
  if (blockIdx.x < 8192) {
    const int i = (blockIdx.x * 256 + threadIdx.x) << 2;
    float4 v = *(const float4*)(in + i);
    half4v o = { (_Float16)v.x, (_Float16)v.y, (_Float16)v.z, (_Float16)v.w };
    *(half4v*)(out + i) = o;
  } else {
    // zero l (8192 floats) + ready flags (64 u32) : 9 blocks cover 9216
    const int i = ((blockIdx.x - 8192) * 256 + threadIdx.x) << 2;
    *(float4*)(l + i) = float4{0.f, 0.f, 0.f, 0.f};
  }
}

// W [1024(k),1024(n)] fp32 -> Wt [n][k] f16 for 3 weights -> [3072][1024]
__global__ __launch_bounds__(256)
void transpose_w(const float* __restrict__ W0, const float* __restrict__ W1,
                 const float* __restrict__ W2, _Float16* __restrict__ Wt) {
  const float* W = blockIdx.z == 0 ? W0 : (blockIdx.z == 1 ? W1 : W2);
  _Float16* out = Wt + (long long)blockIdx.z * 1048576;
  __shared__ _Float16 t[32][33];
  const int tx = threadIdx.x, ty = threadIdx.y;
  const int n0 = blockIdx.x << 5, k0 = blockIdx.y << 5;
#pragma unroll
  for (int i = 0; i < 4; ++i)
    t[ty + i * 8][tx] = (_Float16)W[(long long)(k0 + ty + i * 8) * 1024 + n0 + tx];
  __syncthreads();
#pragma unroll
  for (int i = 0; i < 4; ++i)
    out[(long long)(n0 + ty + i * 8) * 1024 + k0 + tx] = t[tx][ty + i * 8];
}

// ---------------------------------------------------------------- QKV GEMM
// Unchanged (736 TF, conflicts 0): 128x128 tile, BK=64, 4 waves 2x2.
__global__ __launch_bounds__(256)
void gemm_qkv(const _Float16* __restrict__ A, const _Float16* __restrict__ B,
              _Float16* __restrict__ Q, _Float16* __restrict__ Kh,
              _Float16* __restrict__ Vt) {
  const int bm = blockIdx.y, bn = blockIdx.x;
  const _Float16* Ab = A + (long long)bm * 128 * 1024;
  const _Float16* Bb = B + (long long)bn * 128 * 1024;

  __shared__ _Float16 As[128][64];
  __shared__ _Float16 Bs[128][64];

  const int tid = threadIdx.x;
  const int wave = tid >> 6, lane = tid & 63;
  const int quad = lane >> 4, lr = lane & 15;
  const int wm = (wave >> 1) << 6, wn = (wave & 1) << 6;
  const int srow = lane >> 3;
  const int goff = ((lane & 7) ^ srow) << 3;

  floatx4 acc[4][4] = {};
  const _Float16* ga = Ab + (long long)(wave * 8 + srow) * 1024 + goff;
  const _Float16* gb = Bb + (long long)(wave * 8 + srow) * 1024 + goff;

  for (int k0 = 0; k0 < 1024; k0 += 64) {
    __syncthreads();
#pragma unroll
    for (int c = 0; c < 4; ++c) {
      load16_lds(&As[wave * 8 + 32 * c][0], ga + c * 32 * 1024);
      load16_lds(&Bs[wave * 8 + 32 * c][0], gb + c * 32 * 1024);
    }
    ga += 64; gb += 64;
    __syncthreads();

#pragma unroll
    for (int kk = 0; kk < 2; ++kk) {
      half8 af[4], bf[4];
#pragma unroll
      for (int i = 0; i < 4; ++i) {
        const int ra = wm + (i << 4) + lr;
        const int rb = wn + (i << 4) + lr;
        af[i] = *(const half8*)&As[ra][(((kk << 2) + quad) ^ (ra & 7)) << 3];
        bf[i] = *(const half8*)&Bs[rb][(((kk << 2) + quad) ^ (rb & 7)) << 3];
      }
#pragma unroll
      for (int i = 0; i < 4; ++i)
#pragma unroll
        for (int j = 0; j < 4; ++j)
          acc[i][j] = __builtin_amdgcn_mfma_f32_16x16x32_f16(af[i], bf[j], acc[i][j], 0, 0, 0);
    }
  }

  const int colb = bn * 128 + wn + lr;
  const int rowb = bm * 128 + wm + (quad << 2);

  if (bn < 16) {
    _Float16* C = (bn < 8) ? Q : Kh;
    const int cb = colb & 1023;
#pragma unroll
    for (int i = 0; i < 4; ++i)
#pragma unroll
      for (int j = 0; j < 4; ++j)
#pragma unroll
        for (int r = 0; r < 4; ++r)
          C[(long long)(rowb + (i << 4) + r) * 1024 + cb + (j << 4)] =
              (_Float16)acc[i][j][r];
  } else {
    const int b = rowb >> 11;
    const int tb = rowb & 2047;
#pragma unroll
    for (int i = 0; i < 4; ++i) {
      const int tok = tb + (i << 4);
#pragma unroll
      for (int j = 0; j < 4; ++j) {
        const int d = (colb & 1023) + (j << 4);
        half4v v = { (_Float16)acc[i][j][0], (_Float16)acc[i][j][1],
                     (_Float16)acc[i][j][2], (_Float16)acc[i][j][3] };
        *(half4v*)&Vt[(long long)b * 2097152 + (long long)d * 2048 + tok] = v;
      }
    }
  }
}

// ---------------------------------------------------------------- fused S+PV
// blockIdx.x < 544:  S role.  idx -> bz = idx&3, t = idx>>2 (0..135)
//   triangular decode bm ascending; compute exp(mask(QK^T/32)) tile,
//   store P f16, atomic row sums; threadfence; atomicAdd ready[bz*16+bm].
// blockIdx.x >= 544: PV role. p = idx-544 -> bz = p&3, r = p>>2 (0..127),
//   bm = r>>3 (ascending = unlock order), dn = r&7; spin until
//   ready[bz*16+bm] == bm+1; compute (P V)/l for Keff = 128*(bm+1).
__global__ __launch_bounds__(256)
void attn_sp(const _Float16* __restrict__ Q, const _Float16* __restrict__ Kh,
             const _Float16* __restrict__ Vt, _Float16* __restrict__ P,
             float* __restrict__ l, unsigned int* __restrict__ ready,
             float* __restrict__ out) {
  __shared__ _Float16 As[128][64];
  __shared__ _Float16 Bs[128][64];

  const int tid = threadIdx.x;
  const int wave = tid >> 6, lane = tid & 63;
  const int quad = lane >> 4, lr = lane & 15;
  const int wm = (wave >> 1) << 6, wn = (wave & 1) << 6;
  const int srow = lane >> 3;
  const int goff = ((lane & 7) ^ srow) << 3;

  floatx4 acc[4][4] = {};

  if (blockIdx.x < 544) {
    // ----------------------------------------------------------- S role
    const int bz = blockIdx.x & 3;
    int t = blockIdx.x >> 2;
    int bm = 0;
    for (;;) { const int c = bm + 1; if (t < c) break; t -= c; ++bm; }
    const int bn = t;

    const _Float16* Ab = Q  + (long long)bz * 2097152 + (long long)bm * 128 * 1024;
    const _Float16* Bb = Kh + (long long)bz * 2097152 + (long long)bn * 128 * 1024;

    const _Float16* ga = Ab + (long long)(wave * 8 + srow) * 1024 + goff;
    const _Float16* gb = Bb + (long long)(wave * 8 + srow) * 1024 + goff;

    for (int k0 = 0; k0 < 1024; k0 += 64) {
      __syncthreads();
#pragma unroll
      for (int c = 0; c < 4; ++c) {
        load16_lds(&As[wave * 8 + 32 * c][0], ga + c * 32 * 1024);
        load16_lds(&Bs[wave * 8 + 32 * c][0], gb + c * 32 * 1024);
      }
      ga += 64; gb += 64;
      __syncthreads();

#pragma unroll
      for (int kk = 0; kk < 2; ++kk) {
        half8 af[4], bf[4];
#pragma unroll
        for (int i = 0; i < 4; ++i) {
          const int ra = wm + (i << 4) + lr;
          const int rb = wn + (i << 4) + lr;
          af[i] = *(const half8*)&As[ra][(((kk << 2) + quad) ^ (ra & 7)) << 3];
          bf[i] = *(const half8*)&Bs[rb][(((kk << 2) + quad) ^ (rb & 7)) << 3];
        }
#pragma unroll
        for (int i = 0; i < 4; ++i)
#pragma unroll
          for (int j = 0; j < 4; ++j)
            acc[i][j] = __builtin_amdgcn_mfma_f32_16x16x32_f16(af[i], bf[j], acc[i][j], 0, 0, 0);
      }
    }

    const int colb = bn * 128 + wn + lr;
    const int rowb = bm * 128 + wm + (quad << 2);
    _Float16* Pb = P + (long long)bz * 4194304;
    const float scl = 0.03125f;

    float rs[4][4];
#pragma unroll
    for (int i = 0; i < 4; ++i)
#pragma unroll
      for (int r = 0; r < 4; ++r) rs[i][r] = 0.f;

#pragma unroll
    for (int i = 0; i < 4; ++i)
#pragma unroll
      for (int j = 0; j < 4; ++j)
#pragma unroll
        for (int r = 0; r < 4; ++r) {
          const int q = rowb + (i << 4) + r;
          const int kcol = colb + (j << 4);
          const float pv = (kcol <= q) ? __expf(acc[i][j][r] * scl) : 0.f;
          Pb[(long long)q * 2048 + kcol] = (_Float16)pv;
          rs[i][r] += pv;
        }

#pragma unroll
    for (int i = 0; i < 4; ++i)
#pragma unroll
      for (int r = 0; r < 4; ++r) {
#pragma unroll
        for (int off = 1; off < 16; off <<= 1)
          rs[i][r] += __shfl_xor(rs[i][r], off);
      }
    if (lr == 0) {
      float* lb = l + bz * 2048;
#pragma unroll
      for (int i = 0; i < 4; ++i)
#pragma unroll
        for (int r = 0; r < 4; ++r)
          atomicAdd(&lb[rowb + (i << 4) + r], rs[i][r]);
    }

    // publish: make P stores + l adds visible device-wide, then count up.
    __threadfence();
    __syncthreads();
    if (tid == 0) atomicAdd(&ready[bz * 16 + bm], 1u);

  } else {
    // ----------------------------------------------------------- PV role
    const int p = blockIdx.x - 544;
    const int bz = p & 3;
    const int r0 = p >> 2;           // 0..127
    const int bm = r0 >> 3;          // ascending = unlock order
    const int dn = r0 & 7;
    const int Keff = 128 * (bm + 1);

    if (tid == 0) {
      while (__hip_atomic_load(&ready[bz * 16 + bm], __ATOMIC_ACQUIRE,
                               __HIP_MEMORY_SCOPE_AGENT) < (unsigned)(bm + 1)) {
        __builtin_amdgcn_s_sleep(8);
      }
    }
    __syncthreads();
    __threadfence();  // invalidate caches before reading P / l

    const _Float16* Ab = P  + (long long)bz * 4194304 + (long long)bm * 128 * 2048;
    const _Float16* Bb = Vt + (long long)bz * 2097152 + (long long)dn * 128 * 2048;

    const _Float16* ga = Ab + (long long)(wave * 8 + srow) * 2048 + goff;
    const _Float16* gb = Bb + (long long)(wave * 8 + srow) * 2048 + goff;

    for (int k0 = 0; k0 < Keff; k0 += 64) {
      __syncthreads();
#pragma unroll
      for (int c = 0; c < 4; ++c) {
        load16_lds(&As[wave * 8 + 32 * c][0], ga + (long long)c * 32 * 2048);
        load16_lds(&Bs[wave * 8 + 32 * c][0], gb + (long long)c * 32 * 2048);
      }
      ga += 64; gb += 64;
      __syncthreads();

#pragma unroll
      for (int kk = 0; kk < 2; ++kk) {
        half8 af[4], bf[4];
#pragma unroll
        for (int i = 0; i < 4; ++i) {
          const int ra = wm + (i << 4) + lr;
          const int rb = wn + (i << 4) + lr;
          af[i] = *(const half8*)&As[ra][(((kk << 2) + quad) ^ (ra & 7)) << 3];
          bf[i] = *(const half8*)&Bs[rb][(((kk << 2) + quad) ^ (rb & 7)) << 3];
        }
#pragma unroll
        for (int i = 0; i < 4; ++i)
#pragma unroll
          for (int j = 0; j < 4; ++j)
            acc[i][j] = __builtin_amdgcn_mfma_f32_16x16x32_f16(af[i], bf[j], acc[i][j], 0, 0, 0);
      }
    }

    const int colb = dn * 128 + wn + lr;
    const int rowb = bm * 128 + wm + (quad << 2);
    const float* lb = l + bz * 2048;
    float* Cb = out + (long long)bz * 2097152;

    float linv[4][4];
#pragma unroll
    for (int i = 0; i < 4; ++i)
#pragma unroll
      for (int r = 0; r < 4; ++r)
        linv[i][r] = 1.0f / lb[rowb + (i << 4) + r];

#pragma unroll
    for (int i = 0; i < 4; ++i)
#pragma unroll
      for (int j = 0; j < 4; ++j)
#pragma unroll
        for (int r = 0; r < 4; ++r)
          Cb[(long long)(rowb + (i << 4) + r) * 1024 + colb + (j << 4)] =
              acc[i][j][r] * linv[i][r];
  }
}

// ---------------------------------------------------------------- launch

extern "C" void kernel_launch(void* const* d_in, const int* in_sizes, int n_in,
                              void* d_out, int out_size, void* d_ws, size_t ws_size,
                              hipStream_t stream) {
  const float* x  = (const float*)d_in[0];
  const float* Wq = (const float*)d_in[1];
  const float* Wk = (const float*)d_in[2];
  const float* Wv = (const float*)d_in[3];
  float* out = (float*)d_out;

  char* ws = (char*)d_ws;
  _Float16* xh = (_Float16*)(ws);               // 8192x1024 f16   (16 MiB)
  _Float16* Wt = (_Float16*)(ws + 16777216);    // 3072x1024 f16   ( 6 MiB)
  _Float16* Q  = (_Float16*)(ws + 23068672);    // 8192x1024 f16
  _Float16* Kh = (_Float16*)(ws + 39845888);    // 8192x1024 f16
  _Float16* Vt = (_Float16*)(ws + 56623104);    // 4x1024x2048 f16
  _Float16* P  = (_Float16*)(ws + 73400320);    // 4x2048x2048 f16 unnormalized
  float*    l  = (float*)   (ws + 106954752);   // 4x2048 fp32 row sums
  unsigned int* ready = (unsigned int*)(ws + 106954752 + 32768);  // 64 flags

  conv_f32_f16<<<8201, 256, 0, stream>>>(x, xh, l);  // also zeros l+ready
  transpose_w<<<dim3(32, 32, 3), dim3(32, 8), 0, stream>>>(Wq, Wk, Wv, Wt);

  // fused QKV: [8192,1024] x [3072,1024]^T
  gemm_qkv<<<dim3(24, 64), 256, 0, stream>>>(xh, Wt, Q, Kh, Vt);

  // fused S+PV: 544 S blocks + 512 PV blocks, flag-ordered by q-row tile.
  attn_sp<<<1056, 256, 0, stream>>>(Q, Kh, Vt, P, l, ready, out);
}

// Round 11
// 237.640 us; speedup vs baseline: 1.4390x; 1.4390x over previous
//
#include <hip/hip_runtime.h>

// CausalSelfAttention B=4, N=2048, D=1024, scale 1/32.
// f16 convert(+zero l) -> fused QKV GEMM (128x128, BK=64, global_load_lds) ->
// S=QK^T 128x128 (fused mask+exp + atomic row sums) -> PV 128x128 (causal
// K-limit, heavy-first) / rowsum.
//
// R11: S/PV staging switched from global_load_lds to buffer_load->VGPR +
// ds_write_b128, software-pipelined (write k | barrier | load k+1 | mfma k).
// Evidence (R4-R10): per-block staging rate pinned at ~2.9 B/cyc under every
// structure => ~1 outstanding global_load_lds per wave (serialized at HBM
// latency). VGPR-path loads fly concurrently (AITER/hipBLASLt pattern).
// QKV kept on global_load_lds as a control (6 blocks/CU, L2-resident B).

typedef __attribute__((ext_vector_type(8))) _Float16 half8;
typedef __attribute__((ext_vector_type(4))) _Float16 half4v;
typedef __attribute__((ext_vector_type(4))) float floatx4;

#define AS1 __attribute__((address_space(1)))
#define AS3 __attribute__((address_space(3)))

__device__ __forceinline__ void load16_lds(void* lds, const void* g) {
  __builtin_amdgcn_global_load_lds((AS1 void*)g, (AS3 void*)lds, 16, 0, 0);
}

// ---------------------------------------------------------------- conv + zero

__global__ __launch_bounds__(256)
void conv_f32_f16(const float* __restrict__ in, _Float16* __restrict__ out,
                  float* __restrict__ l) {
  if (blockIdx.x < 8192) {
    const int i = (blockIdx.x * 256 + threadIdx.x) << 2;
    float4 v = *(const float4*)(in + i);
    half4v o = { (_Float16)v.x, (_Float16)v.y, (_Float16)v.z, (_Float16)v.w };
    *(half4v*)(out + i) = o;
  } else {
    const int i = ((blockIdx.x - 8192) * 256 + threadIdx.x) << 2;
    *(float4*)(l + i) = float4{0.f, 0.f, 0.f, 0.f};
  }
}

// W [1024(k),1024(n)] fp32 -> Wt [n][k] f16 for 3 weights -> [3072][1024]
__global__ __launch_bounds__(256)
void transpose_w(const float* __restrict__ W0, const float* __restrict__ W1,
                 const float* __restrict__ W2, _Float16* __restrict__ Wt) {
  const float* W = blockIdx.z == 0 ? W0 : (blockIdx.z == 1 ? W1 : W2);
  _Float16* out = Wt + (long long)blockIdx.z * 1048576;
  __shared__ _Float16 t[32][33];
  const int tx = threadIdx.x, ty = threadIdx.y;
  const int n0 = blockIdx.x << 5, k0 = blockIdx.y << 5;
#pragma unroll
  for (int i = 0; i < 4; ++i)
    t[ty + i * 8][tx] = (_Float16)W[(long long)(k0 + ty + i * 8) * 1024 + n0 + tx];
  __syncthreads();
#pragma unroll
  for (int i = 0; i < 4; ++i)
    out[(long long)(n0 + ty + i * 8) * 1024 + k0 + tx] = t[tx][ty + i * 8];
}

// ---------------------------------------------------------------- QKV GEMM
// Unchanged (736 TF, conflicts 0): 128x128 tile, BK=64, 4 waves 2x2.
__global__ __launch_bounds__(256)
void gemm_qkv(const _Float16* __restrict__ A, const _Float16* __restrict__ B,
              _Float16* __restrict__ Q, _Float16* __restrict__ Kh,
              _Float16* __restrict__ Vt) {
  const int bm = blockIdx.y, bn = blockIdx.x;
  const _Float16* Ab = A + (long long)bm * 128 * 1024;
  const _Float16* Bb = B + (long long)bn * 128 * 1024;

  __shared__ _Float16 As[128][64];
  __shared__ _Float16 Bs[128][64];

  const int tid = threadIdx.x;
  const int wave = tid >> 6, lane = tid & 63;
  const int quad = lane >> 4, lr = lane & 15;
  const int wm = (wave >> 1) << 6, wn = (wave & 1) << 6;
  const int srow = lane >> 3;
  const int goff = ((lane & 7) ^ srow) << 3;

  floatx4 acc[4][4] = {};
  const _Float16* ga = Ab + (long long)(wave * 8 + srow) * 1024 + goff;
  const _Float16* gb = Bb + (long long)(wave * 8 + srow) * 1024 + goff;

  for (int k0 = 0; k0 < 1024; k0 += 64) {
    __syncthreads();
#pragma unroll
    for (int c = 0; c < 4; ++c) {
      load16_lds(&As[wave * 8 + 32 * c][0], ga + c * 32 * 1024);
      load16_lds(&Bs[wave * 8 + 32 * c][0], gb + c * 32 * 1024);
    }
    ga += 64; gb += 64;
    __syncthreads();

#pragma unroll
    for (int kk = 0; kk < 2; ++kk) {
      half8 af[4], bf[4];
#pragma unroll
      for (int i = 0; i < 4; ++i) {
        const int ra = wm + (i << 4) + lr;
        const int rb = wn + (i << 4) + lr;
        af[i] = *(const half8*)&As[ra][(((kk << 2) + quad) ^ (ra & 7)) << 3];
        bf[i] = *(const half8*)&Bs[rb][(((kk << 2) + quad) ^ (rb & 7)) << 3];
      }
#pragma unroll
      for (int i = 0; i < 4; ++i)
#pragma unroll
        for (int j = 0; j < 4; ++j)
          acc[i][j] = __builtin_amdgcn_mfma_f32_16x16x32_f16(af[i], bf[j], acc[i][j], 0, 0, 0);
    }
  }

  const int colb = bn * 128 + wn + lr;
  const int rowb = bm * 128 + wm + (quad << 2);

  if (bn < 16) {
    _Float16* C = (bn < 8) ? Q : Kh;
    const int cb = colb & 1023;
#pragma unroll
    for (int i = 0; i < 4; ++i)
#pragma unroll
      for (int j = 0; j < 4; ++j)
#pragma unroll
        for (int r = 0; r < 4; ++r)
          C[(long long)(rowb + (i << 4) + r) * 1024 + cb + (j << 4)] =
              (_Float16)acc[i][j][r];
  } else {
    const int b = rowb >> 11;
    const int tb = rowb & 2047;
#pragma unroll
    for (int i = 0; i < 4; ++i) {
      const int tok = tb + (i << 4);
#pragma unroll
      for (int j = 0; j < 4; ++j) {
        const int d = (colb & 1023) + (j << 4);
        half4v v = { (_Float16)acc[i][j][0], (_Float16)acc[i][j][1],
                     (_Float16)acc[i][j][2], (_Float16)acc[i][j][3] };
        *(half4v*)&Vt[(long long)b * 2097152 + (long long)d * 2048 + tok] = v;
      }
    }
  }
}

// ---------------------------------------------------------------- S GEMM
// P_unnorm[128 q x 128 k] = exp(mask(Q K^T/32)) f16 + atomic row sums.
// VGPR-prefetch staging: ds_write(tile k) | barrier | load(tile k+1) | MFMA.
// Compact triangular grid bn <= bm (136 tiles/batch).
__global__ __launch_bounds__(256)
void gemm_s_exp(const _Float16* __restrict__ Q, const _Float16* __restrict__ Kh,
                _Float16* __restrict__ P, float* __restrict__ l) {
  int t = blockIdx.x;
  int bm = 0;
  for (;;) { const int c = bm + 1; if (t < c) break; t -= c; ++bm; }
  const int bn = t;
  const int bz = blockIdx.y;

  const _Float16* Ab = Q  + (long long)bz * 2097152 + (long long)bm * 128 * 1024;
  const _Float16* Bb = Kh + (long long)bz * 2097152 + (long long)bn * 128 * 1024;

  __shared__ _Float16 As[128][64];
  __shared__ _Float16 Bs[128][64];

  const int tid = threadIdx.x;
  const int wave = tid >> 6, lane = tid & 63;
  const int quad = lane >> 4, lr = lane & 15;
  const int wm = (wave >> 1) << 6, wn = (wave & 1) << 6;
  const int srow = lane >> 3;
  const int schunk = lane & 7;                 // LDS slot this lane fills
  const int goff = (schunk ^ srow) << 3;       // global chunk -> slot^(r&7)

  floatx4 acc[4][4] = {};
  const _Float16* ga = Ab + (long long)(wave * 8 + srow) * 1024 + goff;
  const _Float16* gb = Bb + (long long)(wave * 8 + srow) * 1024 + goff;

  half8 pa[4], pb[4];
#pragma unroll
  for (int c = 0; c < 4; ++c) {
    pa[c] = *(const half8*)(ga + c * 32 * 1024);
    pb[c] = *(const half8*)(gb + c * 32 * 1024);
  }

  for (int it = 0; it < 16; ++it) {
    __syncthreads();
#pragma unroll
    for (int c = 0; c < 4; ++c) {
      *(half8*)&As[wave * 8 + 32 * c + srow][schunk << 3] = pa[c];
      *(half8*)&Bs[wave * 8 + 32 * c + srow][schunk << 3] = pb[c];
    }
    __syncthreads();
    if (it + 1 < 16) {
      const int k1 = (it + 1) << 6;
#pragma unroll
      for (int c = 0; c < 4; ++c) {
        pa[c] = *(const half8*)(ga + c * 32 * 1024 + k1);
        pb[c] = *(const half8*)(gb + c * 32 * 1024 + k1);
      }
    }

#pragma unroll
    for (int kk = 0; kk < 2; ++kk) {
      half8 af[4], bf[4];
#pragma unroll
      for (int i = 0; i < 4; ++i) {
        const int ra = wm + (i << 4) + lr;
        const int rb = wn + (i << 4) + lr;
        af[i] = *(const half8*)&As[ra][(((kk << 2) + quad) ^ (ra & 7)) << 3];
        bf[i] = *(const half8*)&Bs[rb][(((kk << 2) + quad) ^ (rb & 7)) << 3];
      }
#pragma unroll
      for (int i = 0; i < 4; ++i)
#pragma unroll
        for (int j = 0; j < 4; ++j)
          acc[i][j] = __builtin_amdgcn_mfma_f32_16x16x32_f16(af[i], bf[j], acc[i][j], 0, 0, 0);
    }
  }

  // epilogue: p = exp(s/32) masked; f16 store; row-sum -> atomicAdd l[row]
  const int colb = bn * 128 + wn + lr;
  const int rowb = bm * 128 + wm + (quad << 2);
  _Float16* Pb = P + (long long)bz * 4194304;
  const float scl = 0.03125f;

  float rs[4][4];
#pragma unroll
  for (int i = 0; i < 4; ++i)
#pragma unroll
    for (int r = 0; r < 4; ++r) rs[i][r] = 0.f;

#pragma unroll
  for (int i = 0; i < 4; ++i)
#pragma unroll
    for (int j = 0; j < 4; ++j)
#pragma unroll
      for (int r = 0; r < 4; ++r) {
        const int q = rowb + (i << 4) + r;
        const int kcol = colb + (j << 4);
        const float pv = (kcol <= q) ? __expf(acc[i][j][r] * scl) : 0.f;
        Pb[(long long)q * 2048 + kcol] = (_Float16)pv;
        rs[i][r] += pv;
      }

#pragma unroll
  for (int i = 0; i < 4; ++i)
#pragma unroll
    for (int r = 0; r < 4; ++r) {
#pragma unroll
      for (int off = 1; off < 16; off <<= 1)
        rs[i][r] += __shfl_xor(rs[i][r], off);
    }
  if (lr == 0) {
    float* lb = l + bz * 2048;
#pragma unroll
    for (int i = 0; i < 4; ++i)
#pragma unroll
      for (int r = 0; r < 4; ++r)
        atomicAdd(&lb[rowb + (i << 4) + r], rs[i][r]);
  }
}

// ---------------------------------------------------------------- PV GEMM
// out[128 q x 128 d] = (P_unnorm V) / l[q]; Keff = 128*(bm+1); heavy-first.
// Same VGPR-prefetch staging; lda/ldb = 2048.
__global__ __launch_bounds__(256)
void gemm_pv(const _Float16* __restrict__ P, const _Float16* __restrict__ Vt,
             const float* __restrict__ l, float* __restrict__ out) {
  const int dn = blockIdx.x;           // 0..7
  const int bm = 15 - blockIdx.y;      // heavy (large Keff) first
  const int bz = blockIdx.z;
  const int niter = 2 * (bm + 1);      // Keff/64

  const _Float16* Ab = P  + (long long)bz * 4194304 + (long long)bm * 128 * 2048;
  const _Float16* Bb = Vt + (long long)bz * 2097152 + (long long)dn * 128 * 2048;

  __shared__ _Float16 As[128][64];
  __shared__ _Float16 Bs[128][64];

  const int tid = threadIdx.x;
  const int wave = tid >> 6, lane = tid & 63;
  const int quad = lane >> 4, lr = lane & 15;
  const int wm = (wave >> 1) << 6, wn = (wave & 1) << 6;
  const int srow = lane >> 3;
  const int schunk = lane & 7;
  const int goff = (schunk ^ srow) << 3;

  floatx4 acc[4][4] = {};
  const _Float16* ga = Ab + (long long)(wave * 8 + srow) * 2048 + goff;
  const _Float16* gb = Bb + (long long)(wave * 8 + srow) * 2048 + goff;

  half8 pa[4], pb[4];
#pragma unroll
  for (int c = 0; c < 4; ++c) {
    pa[c] = *(const half8*)(ga + (long long)c * 32 * 2048);
    pb[c] = *(const half8*)(gb + (long long)c * 32 * 2048);
  }

  for (int it = 0; it < niter; ++it) {
    __syncthreads();
#pragma unroll
    for (int c = 0; c < 4; ++c) {
      *(half8*)&As[wave * 8 + 32 * c + srow][schunk << 3] = pa[c];
      *(half8*)&Bs[wave * 8 + 32 * c + srow][schunk << 3] = pb[c];
    }
    __syncthreads();
    if (it + 1 < niter) {
      const int k1 = (it + 1) << 6;
#pragma unroll
      for (int c = 0; c < 4; ++c) {
        pa[c] = *(const half8*)(ga + (long long)c * 32 * 2048 + k1);
        pb[c] = *(const half8*)(gb + (long long)c * 32 * 2048 + k1);
      }
    }

#pragma unroll
    for (int kk = 0; kk < 2; ++kk) {
      half8 af[4], bf[4];
#pragma unroll
      for (int i = 0; i < 4; ++i) {
        const int ra = wm + (i << 4) + lr;
        const int rb = wn + (i << 4) + lr;
        af[i] = *(const half8*)&As[ra][(((kk << 2) + quad) ^ (ra & 7)) << 3];
        bf[i] = *(const half8*)&Bs[rb][(((kk << 2) + quad) ^ (rb & 7)) << 3];
      }
#pragma unroll
      for (int i = 0; i < 4; ++i)
#pragma unroll
        for (int j = 0; j < 4; ++j)
          acc[i][j] = __builtin_amdgcn_mfma_f32_16x16x32_f16(af[i], bf[j], acc[i][j], 0, 0, 0);
    }
  }

  const int colb = dn * 128 + wn + lr;
  const int rowb = bm * 128 + wm + (quad << 2);
  const float* lb = l + bz * 2048;
  float* Cb = out + (long long)bz * 2097152;

  float linv[4][4];
#pragma unroll
  for (int i = 0; i < 4; ++i)
#pragma unroll
    for (int r = 0; r < 4; ++r)
      linv[i][r] = 1.0f / lb[rowb + (i << 4) + r];

#pragma unroll
  for (int i = 0; i < 4; ++i)
#pragma unroll
    for (int j = 0; j < 4; ++j)
#pragma unroll
      for (int r = 0; r < 4; ++r)
        Cb[(long long)(rowb + (i << 4) + r) * 1024 + colb + (j << 4)] =
            acc[i][j][r] * linv[i][r];
}

// ---------------------------------------------------------------- launch

extern "C" void kernel_launch(void* const* d_in, const int* in_sizes, int n_in,
                              void* d_out, int out_size, void* d_ws, size_t ws_size,
                              hipStream_t stream) {
  const float* x  = (const float*)d_in[0];
  const float* Wq = (const float*)d_in[1];
  const float* Wk = (const float*)d_in[2];
  const float* Wv = (const float*)d_in[3];
  float* out = (float*)d_out;

  char* ws = (char*)d_ws;
  _Float16* xh = (_Float16*)(ws);               // 8192x1024 f16   (16 MiB)
  _Float16* Wt = (_Float16*)(ws + 16777216);    // 3072x1024 f16   ( 6 MiB)
  _Float16* Q  = (_Float16*)(ws + 23068672);    // 8192x1024 f16
  _Float16* Kh = (_Float16*)(ws + 39845888);    // 8192x1024 f16
  _Float16* Vt = (_Float16*)(ws + 56623104);    // 4x1024x2048 f16
  _Float16* P  = (_Float16*)(ws + 73400320);    // 4x2048x2048 f16 unnormalized
  float*    l  = (float*)   (ws + 106954752);   // 4x2048 fp32 row sums

  conv_f32_f16<<<8200, 256, 0, stream>>>(x, xh, l);
  transpose_w<<<dim3(32, 32, 3), dim3(32, 8), 0, stream>>>(Wq, Wk, Wv, Wt);

  // fused QKV: [8192,1024] x [3072,1024]^T
  gemm_qkv<<<dim3(24, 64), 256, 0, stream>>>(xh, Wt, Q, Kh, Vt);

  // P_unnorm = exp(mask(Q K^T / 32)) + row sums; compact triangular grid
  gemm_s_exp<<<dim3(136, 4), 256, 0, stream>>>(Q, Kh, P, l);

  // out = (P V) / l; causal K-limit at 128 gran, heavy-first
  gemm_pv<<<dim3(8, 16, 4), 256, 0, stream>>>(P, Vt, l, out);
}